// Round 7
// baseline (349.885 us; speedup 1.0000x reference)
//
#include <hip/hip_runtime.h>
#include <hip/hip_bf16.h>
#include <math.h>

#define NRL 4
#define LL 4096
#define NFFT 4104
#define LP 4224
#define NB 64
#define WD 64
#define BST (LP*WD*2)        // 540672 bytes per batch plane
#define DCH 12
#define DKS 11
#define PI2 6.28318530717958647692f

typedef __attribute__((ext_vector_type(8))) short short8;
typedef __attribute__((ext_vector_type(4))) float f32x4;

__device__ inline unsigned short f2bf(float f){
  unsigned int u = __float_as_uint(f);
  return (unsigned short)((u + 0x7FFFu + ((u>>16)&1u)) >> 16);
}
// tanh-form gelu: |err vs erf-gelu| <= ~5e-4
__device__ inline float gelu_f(float v){
  float v2 = v*v;
  float z = v * fmaf(0.07135481627f, v2, 1.5957691216f);
  float e = __expf(-z);
  return v * __builtin_amdgcn_rcpf(1.0f + e);
}

// ---- one prologue kernel: tf (1056 blocks) | tif (1056) | conv-w frags (64)
__global__ void k_tables(const float* __restrict__ cw,
                         unsigned short* __restrict__ tf,
                         unsigned short* __restrict__ tif,
                         unsigned short* __restrict__ whi, unsigned short* __restrict__ wlo){
  int bid = blockIdx.x;
  if (bid < 1056){
    int idx = bid*256 + threadIdx.x;          // 270336
    int e = idx & 7; int t = idx >> 3;
    int lane = t & 63; int t2 = t >> 6;
    int js = t2 & 3; int ks = t2 >> 2;
    int l = ks*32 + 8*(lane>>4) + e;
    int j = js*16 + (lane & 15);
    int m = j >> 1;
    float v = 0.f;
    if (l < NFFT){
      int r = (m*l) % NFFT;
      float ang = PI2 * ((float)r / (float)NFFT);
      v = (j & 1) ? -__sinf(ang) : __cosf(ang);
    }
    tf[idx] = f2bf(v);
  } else if (bid < 2112){
    int idx = (bid-1056)*256 + threadIdx.x;   // 270336
    int e = idx & 7; int t = idx >> 3;
    int l = t % LP; int rq = t / LP;
    int q = rq & 3; int ks2 = rq >> 2;
    int j2 = ks2*32 + 8*q + e;
    int m = j2 >> 1;
    float v = 0.f;
    if (l < NFFT){
      int r = (m*l) % NFFT;
      float ang = PI2 * ((float)r / (float)NFFT);
      float inv = 1.0f/(float)NFFT;
      v = (j2 & 1) ? (-2.f*inv*__sinf(ang)) : ((m==0?inv:2.f*inv)*__cosf(ang));
    }
    tif[idx] = f2bf(v);
  } else {
    int idx = (bid-2112)*256 + threadIdx.x;   // 16384
    int e = idx & 7; int lane = (idx>>3)&63; int os = (idx>>9)&3;
    int ks2 = (idx>>11)&1; int ly = idx>>12;
    int k = ks2*32 + 8*(lane>>4) + e;
    int o = os*16 + (lane&15);
    float v = cw[((size_t)(ly*64 + o))*64 + k];
    unsigned short h = f2bf(v);
    float lo = v - __uint_as_float(((unsigned)h)<<16);
    whi[idx] = h; wlo[idx] = f2bf(lo);
  }
}

// ---- one lift kernel: [l][c] swizzled plane (8448 blocks) | [c][l] plane (8448)
__global__ void k_lift(const float* __restrict__ x, const float* __restrict__ lw,
                       const float* __restrict__ lb,
                       unsigned short* __restrict__ xh, unsigned short* __restrict__ xt){
  int bid = blockIdx.x;
  if (bid < 8448){
    int idx = bid*256 + threadIdx.x;          // 2162688 = 64*4224*8
    int u = idx & 7; int t = idx >> 3;
    int l = t % LP; int b = t / LP;
    char* ph = (char*)xh + (size_t)b*BST + (size_t)l*128;
    int sw = (l & 7) << 4;
    if (l >= LL){
      *(uint4*)(ph + ((u*16)^sw)) = make_uint4(0,0,0,0);
      return;
    }
    float xv = x[(size_t)b*LL + l];
    float g = (float)l * (1.0f/4095.0f);
    unsigned int w_[4];
    #pragma unroll
    for (int p=0;p<4;p++){
      unsigned int hh=0;
      #pragma unroll
      for (int s=0;s<2;s++){
        int c = u*8 + p*2 + s;
        float v = fmaf(lw[2*c], xv, fmaf(lw[2*c+1], g, lb[c]));
        hh |= ((unsigned)f2bf(v)) << (16*s);
      }
      w_[p]=hh;
    }
    *(uint4*)(ph + ((u*16)^sw)) = make_uint4(w_[0],w_[1],w_[2],w_[3]);
  } else {
    int idx = (bid-8448)*256 + threadIdx.x;   // 2162688 = 64*64*528
    int l8 = idx % 528; int t = idx / 528;
    int c = t & 63; int b = t >> 6;
    int l = l8*8;
    short8 v8;
    if (l8 >= 512){
      #pragma unroll
      for (int s=0;s<8;s++) v8[s] = 0;
    } else {
      float4 x0 = *reinterpret_cast<const float4*>(x + (size_t)b*LL + l);
      float4 x1 = *reinterpret_cast<const float4*>(x + (size_t)b*LL + l + 4);
      float w0 = lw[2*c], w1 = lw[2*c+1], bb = lb[c];
      const float gs = 1.0f/4095.0f;
      float xs[8] = {x0.x,x0.y,x0.z,x0.w,x1.x,x1.y,x1.z,x1.w};
      #pragma unroll
      for (int s=0;s<8;s++){
        float v = fmaf(w0, xs[s], fmaf(w1, (float)(l+s)*gs, bb));
        v8[s] = (short)f2bf(v);
      }
    }
    *(short8*)(xt + ((size_t)b*64 + c)*LP + l) = v8;
  }
}

// ---- forward DFT via MFMA reading transposed x: D[c][j] partials per (chunk,b)
__global__ __launch_bounds__(256) void k_dft(const unsigned short* __restrict__ xt,
    const unsigned short* __restrict__ tf, float* __restrict__ xmp){
  int ch = blockIdx.x; int b = blockIdx.y;
  int w = threadIdx.x >> 6; int lane = threadIdx.x & 63;
  int q = lane >> 4; int lr = lane & 15;
  const unsigned short* xrow = xt + ((size_t)b*64 + w*16 + lr)*LP;
  f32x4 acc[4];
  #pragma unroll
  for (int js=0;js<4;js++) acc[js] = (f32x4){0.f,0.f,0.f,0.f};
  for (int ksl=0; ksl<DKS; ksl++){
    int ks = ch*DKS + ksl;
    short8 av = *(const short8*)(xrow + ks*32 + 8*q);
    #pragma unroll
    for (int js=0;js<4;js++){
      short8 bv = *(const short8*)(tf + ((size_t)((ks*4+js)*64 + lane))*8);
      acc[js] = __builtin_amdgcn_mfma_f32_16x16x32_bf16(av, bv, acc[js], 0,0,0);
    }
  }
  #pragma unroll
  for (int js=0;js<4;js++){
    #pragma unroll
    for (int r=0;r<4;r++)
      xmp[(size_t)ch*262144 + ((size_t)(b*64 + w*16 + 4*q + r))*64 + js*16 + lr] = acc[js][r];
  }
}

// ---- reduce 12 partial chunks -> xm, float4 coalesced
__global__ void k_red(const float* __restrict__ xmp, float* __restrict__ xm){
  int i4 = blockIdx.x*256 + threadIdx.x;      // 65536
  f32x4 s = (f32x4){0.f,0.f,0.f,0.f};
  #pragma unroll
  for (int p=0;p<DCH;p++){
    f32x4 v = *(const f32x4*)(xmp + (size_t)p*262144 + (size_t)i4*4);
    s.x += v.x; s.y += v.y; s.z += v.z; s.w += v.w;
  }
  *(f32x4*)(xm + (size_t)i4*4) = s;
}

// ---- mode mix -> om A-operand frags [b][ks2 2][os 4][lane 64][e 8] hi/lo
__global__ void k_mix(const float* __restrict__ xm, const float* __restrict__ wr,
                      const float* __restrict__ wi,
                      unsigned short* __restrict__ mh, unsigned short* __restrict__ ml){
  int idx = blockIdx.x*256 + threadIdx.x;     // 131072
  int m = idx & 31, o = (idx>>5)&63, b = idx>>11;
  const float* xp = xm + ((size_t)(b*64))*64 + 2*m;
  float ar=0.f, ai=0.f;
  for (int i=0;i<64;i++){
    float xr = xp[i*64], xi = xp[i*64+1];
    float wrv = wr[((size_t)(i*64 + o))*32 + m];
    float wiv = wi[((size_t)(i*64 + o))*32 + m];
    ar = fmaf(xr,wrv,ar); ar = fmaf(-xi,wiv,ar);
    ai = fmaf(xr,wiv,ai); ai = fmaf(xi,wrv,ai);
  }
  int j2 = 2*m;
  int ks2 = j2 >> 5, rem = j2 & 31, q = rem >> 3, e = rem & 7;
  int lane = q*16 + (o & 15), os = o >> 4;
  size_t a = ((size_t)(((b*2 + ks2)*4 + os)*64 + lane))*8 + e;
  unsigned short hr = f2bf(ar), hi_ = f2bf(ai);
  float lr_ = ar - __uint_as_float(((unsigned)hr)<<16);
  float li_ = ai - __uint_as_float(((unsigned)hi_)<<16);
  *(ushort2*)(mh + a) = make_ushort2(hr, hi_);
  *(ushort2*)(ml + a) = make_ushort2(f2bf(lr_), f2bf(li_));
}

// ---- fused layer: MFMA from L2/L3; epilogue LDS-transposed, coalesced stores
__global__ __launch_bounds__(256) void k_layer(
    const unsigned short* __restrict__ xlc,
    const unsigned short* __restrict__ wfch, const unsigned short* __restrict__ wfcl,
    const unsigned short* __restrict__ wmh, const unsigned short* __restrict__ wml,
    const unsigned short* __restrict__ tif, const float* __restrict__ cb,
    unsigned short* __restrict__ xnh, unsigned short* __restrict__ xnt,
    float* __restrict__ dout, int last){
  __shared__ __align__(16) char lds[32768];
  int l0 = blockIdx.x * 128; int b = blockIdx.y;
  int tid = threadIdx.x;
  int os = tid >> 6, lane = tid & 63, q = lane >> 4, lr = lane & 15;
  const char* xb = (const char*)xlc + (size_t)b*BST;

  short8 ch_[2], cl_[2], mh_[2], ml_[2];
  #pragma unroll
  for (int ks=0;ks<2;ks++){
    size_t a = ((size_t)((ks*4 + os)*64 + lane))*8;
    ch_[ks] = *(const short8*)(wfch + a);
    cl_[ks] = *(const short8*)(wfcl + a);
    size_t am = ((size_t)(((b*2 + ks)*4 + os)*64 + lane))*8;
    mh_[ks] = *(const short8*)(wmh + am);
    ml_[ks] = *(const short8*)(wml + am);
  }
  f32x4 acc[8];
  #pragma unroll
  for (int ls=0;ls<8;ls++) acc[ls] = (f32x4){0.f,0.f,0.f,0.f};
  int sw = (lr & 7) << 4;
  #pragma unroll
  for (int ks=0;ks<2;ks++){
    int cofs = (64*ks + 16*q) ^ sw;
    #pragma unroll
    for (int ls=0;ls<8;ls++){
      short8 bh = *(const short8*)(xb + (size_t)(l0 + ls*16 + lr)*128 + cofs);
      acc[ls] = __builtin_amdgcn_mfma_f32_16x16x32_bf16(ch_[ks], bh, acc[ls], 0,0,0);
      acc[ls] = __builtin_amdgcn_mfma_f32_16x16x32_bf16(cl_[ks], bh, acc[ls], 0,0,0);
    }
  }
  #pragma unroll
  for (int ks=0;ks<2;ks++){
    #pragma unroll
    for (int ls=0;ls<8;ls++){
      int l = l0 + ls*16 + lr;
      short8 bt = *(const short8*)(tif + ((size_t)((ks*4 + q)*LP + l))*8);
      acc[ls] = __builtin_amdgcn_mfma_f32_16x16x32_bf16(mh_[ks], bt, acc[ls], 0,0,0);
      acc[ls] = __builtin_amdgcn_mfma_f32_16x16x32_bf16(ml_[ks], bt, acc[ls], 0,0,0);
    }
  }
  float bias[4];
  #pragma unroll
  for (int r=0;r<4;r++) bias[r] = cb[os*16 + 4*q + r];

  if (!last){
    // stage both layouts in LDS, then coalesced 16B global stores
    char* ldc = lds;            // [l-l0][c swizzled], 16KB == global x_lc chunk image
    char* ldt = lds + 16384;    // [c][l-l0] u16, 16KB
    int co = os*32 + 8*q;
    #pragma unroll
    for (int ls=0;ls<8;ls++){
      int lrow = ls*16 + lr;
      unsigned short us[4];
      #pragma unroll
      for (int r=0;r<4;r++) us[r] = f2bf(gelu_f(acc[ls][r] + bias[r]));
      unsigned int h0 = (unsigned)us[0] | (((unsigned)us[1])<<16);
      unsigned int h1 = (unsigned)us[2] | (((unsigned)us[3])<<16);
      *(uint2*)(ldc + lrow*128 + (co ^ ((lrow&7)<<4))) = make_uint2(h0,h1);
      #pragma unroll
      for (int r=0;r<4;r++)
        *(unsigned short*)(ldt + (os*16 + 4*q + r)*256 + lrow*2) = us[r];
    }
    __syncthreads();
    char* gh = (char*)xnh + (size_t)b*BST + (size_t)l0*128;
    #pragma unroll
    for (int i=0;i<4;i++)
      *(uint4*)(gh + tid*64 + i*16) = *(const uint4*)(ldc + tid*64 + i*16);
    int c = tid >> 2, boff = (tid & 3)*64;
    char* gt = (char*)(xnt + (size_t)b*64*LP) + ((size_t)c*LP + l0)*2 + boff;
    #pragma unroll
    for (int i=0;i<4;i++)
      *(uint4*)(gt + i*16) = *(const uint4*)(ldt + tid*64 + i*16);
  } else if (l0 < LL){
    // stage fp32 [o][l-l0] (32KB), then coalesced row stores
    float* ldf = (float*)lds;
    #pragma unroll
    for (int ls=0;ls<8;ls++){
      #pragma unroll
      for (int r=0;r<4;r++)
        ldf[(os*16 + 4*q + r)*128 + ls*16 + lr] = acc[ls][r] + bias[r];
    }
    __syncthreads();
    int c = tid >> 2, foff = (tid & 3)*32;
    float* gd = dout + ((size_t)(b*64 + c))*LL + l0 + foff;
    const float* lp = ldf + c*128 + foff;
    #pragma unroll
    for (int i=0;i<8;i++)
      *(float4*)(gd + i*4) = *(const float4*)(lp + i*4);
  }
}

extern "C" void kernel_launch(void* const* d_in, const int* in_sizes, int n_in,
                              void* d_out, int out_size, void* d_ws, size_t ws_size,
                              hipStream_t stream) {
  const float* x   = (const float*)d_in[0];
  const float* lw  = (const float*)d_in[1];
  const float* lb  = (const float*)d_in[2];
  const float* cw  = (const float*)d_in[3];
  const float* cb  = (const float*)d_in[4];
  const float* swr = (const float*)d_in[5];
  const float* swi = (const float*)d_in[6];

  char* ws = (char*)d_ws;
  size_t PL = (size_t)NB*BST;                 // 34,603,008 bytes per plane
  unsigned short* x0lc = (unsigned short*)(ws);
  unsigned short* x0t  = (unsigned short*)(ws + PL);
  unsigned short* x1lc = (unsigned short*)(ws + 2*PL);
  unsigned short* x1t  = (unsigned short*)(ws + 3*PL);
  unsigned short* tf   = (unsigned short*)(ws + 4*PL);
  unsigned short* tif  = (unsigned short*)(ws + 4*PL + 540672);
  unsigned short* wfch = (unsigned short*)(ws + 4*PL + 2*540672);
  unsigned short* wfcl = (unsigned short*)(ws + 4*PL + 2*540672 + 32768);
  unsigned short* wmh  = (unsigned short*)(ws + 4*PL + 2*540672 + 2*32768);
  unsigned short* wml  = (unsigned short*)(ws + 4*PL + 2*540672 + 2*32768 + 524288);
  float*          xm   = (float*)        (ws + 4*PL + 2*540672 + 2*32768 + 2*524288);

  k_tables<<<2176, 256,0,stream>>>(cw, tf, tif, wfch, wfcl);
  k_lift  <<<16896,256,0,stream>>>(x, lw, lb, x0lc, x0t);

  for (int k=0;k<NRL;k++){
    unsigned short* curlc = (k&1) ? x1lc : x0lc;
    unsigned short* curt  = (k&1) ? x1t  : x0t;
    unsigned short* nxtlc = (k&1) ? x0lc : x1lc;
    unsigned short* nxtt  = (k&1) ? x0t  : x1t;
    float* xmp = (float*)nxtlc;   // 12.6MB scratch, consumed by k_red before k_layer overwrites
    k_dft<<<dim3(DCH,NB),256,0,stream>>>(curt, tf, xmp);
    k_red<<<256, 256,0,stream>>>(xmp, xm);
    k_mix<<<512, 256,0,stream>>>(xm, swr + (size_t)k*131072, swi + (size_t)k*131072, wmh, wml);
    k_layer<<<dim3(33,NB),256,0,stream>>>(curlc,
        wfch + (size_t)k*4096, wfcl + (size_t)k*4096, wmh, wml, tif,
        cb + (size_t)k*64, nxtlc, nxtt, (float*)d_out, (k==NRL-1) ? 1 : 0);
  }
}

// Round 8
// 268.603 us; speedup vs baseline: 1.3026x; 1.3026x over previous
//
#include <hip/hip_runtime.h>
#include <hip/hip_bf16.h>
#include <math.h>

#define NRL 4
#define LL 4096
#define NFFT 4104
#define LP 4224
#define NB 64
#define WD 64
#define BST (LP*WD*2)        // 540672 bytes per batch plane
#define DCH 12
#define DKS 11
#define LCH 33               // l-chunks of 128 (fused partial count)
#define PI2 6.28318530717958647692f

typedef __attribute__((ext_vector_type(8))) short short8;
typedef __attribute__((ext_vector_type(4))) float f32x4;
typedef __attribute__((ext_vector_type(2))) float f32x2;

__device__ inline unsigned short f2bf(float f){
  unsigned int u = __float_as_uint(f);
  return (unsigned short)((u + 0x7FFFu + ((u>>16)&1u)) >> 16);
}
// tanh-form gelu: |err vs erf-gelu| <= ~5e-4
__device__ inline float gelu_f(float v){
  float v2 = v*v;
  float z = v * fmaf(0.07135481627f, v2, 1.5957691216f);
  float e = __expf(-z);
  return v * __builtin_amdgcn_rcpf(1.0f + e);
}

// ---- one prologue kernel: tf (1056 blocks) | tif (1056) | conv-w frags (64)
__global__ void k_tables(const float* __restrict__ cw,
                         unsigned short* __restrict__ tf,
                         unsigned short* __restrict__ tif,
                         unsigned short* __restrict__ whi, unsigned short* __restrict__ wlo){
  int bid = blockIdx.x;
  if (bid < 1056){
    int idx = bid*256 + threadIdx.x;          // 270336
    int e = idx & 7; int t = idx >> 3;
    int lane = t & 63; int t2 = t >> 6;
    int js = t2 & 3; int ks = t2 >> 2;
    int l = ks*32 + 8*(lane>>4) + e;
    int j = js*16 + (lane & 15);
    int m = j >> 1;
    float v = 0.f;
    if (l < NFFT){
      int r = (m*l) % NFFT;
      float ang = PI2 * ((float)r / (float)NFFT);
      v = (j & 1) ? -__sinf(ang) : __cosf(ang);
    }
    tf[idx] = f2bf(v);
  } else if (bid < 2112){
    int idx = (bid-1056)*256 + threadIdx.x;   // 270336
    int e = idx & 7; int t = idx >> 3;
    int l = t % LP; int rq = t / LP;
    int q = rq & 3; int ks2 = rq >> 2;
    int j2 = ks2*32 + 8*q + e;
    int m = j2 >> 1;
    float v = 0.f;
    if (l < NFFT){
      int r = (m*l) % NFFT;
      float ang = PI2 * ((float)r / (float)NFFT);
      float inv = 1.0f/(float)NFFT;
      v = (j2 & 1) ? (-2.f*inv*__sinf(ang)) : ((m==0?inv:2.f*inv)*__cosf(ang));
    }
    tif[idx] = f2bf(v);
  } else {
    int idx = (bid-2112)*256 + threadIdx.x;   // 16384
    int e = idx & 7; int lane = (idx>>3)&63; int os = (idx>>9)&3;
    int ks2 = (idx>>11)&1; int ly = idx>>12;
    int k = ks2*32 + 8*(lane>>4) + e;
    int o = os*16 + (lane&15);
    float v = cw[((size_t)(ly*64 + o))*64 + k];
    unsigned short h = f2bf(v);
    float lo = v - __uint_as_float(((unsigned)h)<<16);
    whi[idx] = h; wlo[idx] = f2bf(lo);
  }
}

// ---- one lift kernel: [l][c] swizzled plane (8448 blocks) | [c][l] plane (8448)
__global__ void k_lift(const float* __restrict__ x, const float* __restrict__ lw,
                       const float* __restrict__ lb,
                       unsigned short* __restrict__ xh, unsigned short* __restrict__ xt){
  int bid = blockIdx.x;
  if (bid < 8448){
    int idx = bid*256 + threadIdx.x;          // 2162688 = 64*4224*8
    int u = idx & 7; int t = idx >> 3;
    int l = t % LP; int b = t / LP;
    char* ph = (char*)xh + (size_t)b*BST + (size_t)l*128;
    int sw = (l & 7) << 4;
    if (l >= LL){
      *(uint4*)(ph + ((u*16)^sw)) = make_uint4(0,0,0,0);
      return;
    }
    float xv = x[(size_t)b*LL + l];
    float g = (float)l * (1.0f/4095.0f);
    unsigned int w_[4];
    #pragma unroll
    for (int p=0;p<4;p++){
      unsigned int hh=0;
      #pragma unroll
      for (int s=0;s<2;s++){
        int c = u*8 + p*2 + s;
        float v = fmaf(lw[2*c], xv, fmaf(lw[2*c+1], g, lb[c]));
        hh |= ((unsigned)f2bf(v)) << (16*s);
      }
      w_[p]=hh;
    }
    *(uint4*)(ph + ((u*16)^sw)) = make_uint4(w_[0],w_[1],w_[2],w_[3]);
  } else {
    int idx = (bid-8448)*256 + threadIdx.x;   // 2162688 = 64*64*528
    int l8 = idx % 528; int t = idx / 528;
    int c = t & 63; int b = t >> 6;
    int l = l8*8;
    short8 v8;
    if (l8 >= 512){
      #pragma unroll
      for (int s=0;s<8;s++) v8[s] = 0;
    } else {
      float4 x0 = *reinterpret_cast<const float4*>(x + (size_t)b*LL + l);
      float4 x1 = *reinterpret_cast<const float4*>(x + (size_t)b*LL + l + 4);
      float w0 = lw[2*c], w1 = lw[2*c+1], bb = lb[c];
      const float gs = 1.0f/4095.0f;
      float xs[8] = {x0.x,x0.y,x0.z,x0.w,x1.x,x1.y,x1.z,x1.w};
      #pragma unroll
      for (int s=0;s<8;s++){
        float v = fmaf(w0, xs[s], fmaf(w1, (float)(l+s)*gs, bb));
        v8[s] = (short)f2bf(v);
      }
    }
    *(short8*)(xt + ((size_t)b*64 + c)*LP + l) = v8;
  }
}

// ---- forward DFT via MFMA reading transposed x (layer 0 only)
__global__ __launch_bounds__(256) void k_dft(const unsigned short* __restrict__ xt,
    const unsigned short* __restrict__ tf, float* __restrict__ xmp){
  int ch = blockIdx.x; int b = blockIdx.y;
  int w = threadIdx.x >> 6; int lane = threadIdx.x & 63;
  int q = lane >> 4; int lr = lane & 15;
  const unsigned short* xrow = xt + ((size_t)b*64 + w*16 + lr)*LP;
  f32x4 acc[4];
  #pragma unroll
  for (int js=0;js<4;js++) acc[js] = (f32x4){0.f,0.f,0.f,0.f};
  for (int ksl=0; ksl<DKS; ksl++){
    int ks = ch*DKS + ksl;
    short8 av = *(const short8*)(xrow + ks*32 + 8*q);
    #pragma unroll
    for (int js=0;js<4;js++){
      short8 bv = *(const short8*)(tf + ((size_t)((ks*4+js)*64 + lane))*8);
      acc[js] = __builtin_amdgcn_mfma_f32_16x16x32_bf16(av, bv, acc[js], 0,0,0);
    }
  }
  #pragma unroll
  for (int js=0;js<4;js++){
    #pragma unroll
    for (int r=0;r<4;r++)
      xmp[(size_t)ch*262144 + ((size_t)(b*64 + w*16 + 4*q + r))*64 + js*16 + lr] = acc[js][r];
  }
}

// ---- reduce nch partial chunks -> xm, float2 per thread (512 blocks)
__global__ void k_red(const float* __restrict__ xmp, float* __restrict__ xm, int nch){
  int i2 = blockIdx.x*256 + threadIdx.x;      // 131072
  f32x2 s = (f32x2){0.f,0.f};
  #pragma unroll 3
  for (int p=0;p<nch;p++){
    f32x2 v = *(const f32x2*)(xmp + (size_t)p*262144 + (size_t)i2*2);
    s.x += v.x; s.y += v.y;
  }
  *(f32x2*)(xm + (size_t)i2*2) = s;
}

// ---- mode mix -> om A-operand frags [b][ks2 2][os 4][lane 64][e 8] hi/lo
__global__ void k_mix(const float* __restrict__ xm, const float* __restrict__ wr,
                      const float* __restrict__ wi,
                      unsigned short* __restrict__ mh, unsigned short* __restrict__ ml){
  int idx = blockIdx.x*256 + threadIdx.x;     // 131072
  int m = idx & 31, o = (idx>>5)&63, b = idx>>11;
  const float* xp = xm + ((size_t)(b*64))*64 + 2*m;
  float ar=0.f, ai=0.f;
  for (int i=0;i<64;i++){
    float xr = xp[i*64], xi = xp[i*64+1];
    float wrv = wr[((size_t)(i*64 + o))*32 + m];
    float wiv = wi[((size_t)(i*64 + o))*32 + m];
    ar = fmaf(xr,wrv,ar); ar = fmaf(-xi,wiv,ar);
    ai = fmaf(xr,wiv,ai); ai = fmaf(xi,wrv,ai);
  }
  int j2 = 2*m;
  int ks2 = j2 >> 5, rem = j2 & 31, q = rem >> 3, e = rem & 7;
  int lane = q*16 + (o & 15), os = o >> 4;
  size_t a = ((size_t)(((b*2 + ks2)*4 + os)*64 + lane))*8 + e;
  unsigned short hr = f2bf(ar), hi_ = f2bf(ai);
  float lr_ = ar - __uint_as_float(((unsigned)hr)<<16);
  float li_ = ai - __uint_as_float(((unsigned)hi_)<<16);
  *(ushort2*)(mh + a) = make_ushort2(hr, hi_);
  *(ushort2*)(ml + a) = make_ushort2(f2bf(lr_), f2bf(li_));
}

// ---- fused layer: conv+spectral MFMA, r6 direct stores, PLUS fused partial
// DFT of the freshly computed y (so next layer needs no x_t plane / k_dft).
__global__ __launch_bounds__(256) void k_layer(
    const unsigned short* __restrict__ xlc,
    const unsigned short* __restrict__ wfch, const unsigned short* __restrict__ wfcl,
    const unsigned short* __restrict__ wmh, const unsigned short* __restrict__ wml,
    const unsigned short* __restrict__ tif, const unsigned short* __restrict__ tf,
    const float* __restrict__ cb,
    unsigned short* __restrict__ xnh, float* __restrict__ xmp2,
    float* __restrict__ dout, int last){
  __shared__ __align__(16) unsigned short ldt[64*136];  // [c][l-l0], stride 272B (pad 16B)
  int l0 = blockIdx.x * 128; int b = blockIdx.y;
  int tid = threadIdx.x;
  int os = tid >> 6, lane = tid & 63, q = lane >> 4, lr = lane & 15;
  const char* xb = (const char*)xlc + (size_t)b*BST;

  short8 ch_[2], cl_[2], mh_[2], ml_[2];
  #pragma unroll
  for (int ks=0;ks<2;ks++){
    size_t a = ((size_t)((ks*4 + os)*64 + lane))*8;
    ch_[ks] = *(const short8*)(wfch + a);
    cl_[ks] = *(const short8*)(wfcl + a);
    size_t am = ((size_t)(((b*2 + ks)*4 + os)*64 + lane))*8;
    mh_[ks] = *(const short8*)(wmh + am);
    ml_[ks] = *(const short8*)(wml + am);
  }
  f32x4 acc[8];
  #pragma unroll
  for (int ls=0;ls<8;ls++) acc[ls] = (f32x4){0.f,0.f,0.f,0.f};
  int sw = (lr & 7) << 4;
  #pragma unroll
  for (int ks=0;ks<2;ks++){
    int cofs = (64*ks + 16*q) ^ sw;
    #pragma unroll
    for (int ls=0;ls<8;ls++){
      short8 bh = *(const short8*)(xb + (size_t)(l0 + ls*16 + lr)*128 + cofs);
      acc[ls] = __builtin_amdgcn_mfma_f32_16x16x32_bf16(ch_[ks], bh, acc[ls], 0,0,0);
      acc[ls] = __builtin_amdgcn_mfma_f32_16x16x32_bf16(cl_[ks], bh, acc[ls], 0,0,0);
    }
  }
  #pragma unroll
  for (int ks=0;ks<2;ks++){
    #pragma unroll
    for (int ls=0;ls<8;ls++){
      int l = l0 + ls*16 + lr;
      short8 bt = *(const short8*)(tif + ((size_t)((ks*4 + q)*LP + l))*8);
      acc[ls] = __builtin_amdgcn_mfma_f32_16x16x32_bf16(mh_[ks], bt, acc[ls], 0,0,0);
      acc[ls] = __builtin_amdgcn_mfma_f32_16x16x32_bf16(ml_[ks], bt, acc[ls], 0,0,0);
    }
  }
  float bias[4];
  #pragma unroll
  for (int r=0;r<4;r++) bias[r] = cb[os*16 + 4*q + r];

  if (!last){
    int co = os*32 + 8*q;
    char* nb = (char*)xnh + (size_t)b*BST;
    #pragma unroll
    for (int ls=0;ls<8;ls++){
      int lrow = ls*16 + lr; int l = l0 + lrow;
      unsigned short us[4];
      #pragma unroll
      for (int r=0;r<4;r++)
        us[r] = (l < NFFT) ? f2bf(gelu_f(acc[ls][r] + bias[r])) : (unsigned short)0;
      if (l < NFFT){
        unsigned int h0 = (unsigned)us[0] | (((unsigned)us[1])<<16);
        unsigned int h1 = (unsigned)us[2] | (((unsigned)us[3])<<16);
        *(uint2*)(nb + (size_t)l*128 + (co ^ ((lrow&7)<<4))) = make_uint2(h0,h1);
      }
      #pragma unroll
      for (int r=0;r<4;r++)
        ldt[(os*16 + 4*q + r)*136 + lrow] = us[r];
    }
    __syncthreads();
    // partial DFT over this l-chunk: D[c][j] = sum_l y[c][l]*tf[l][j]
    // wave os reads only rows os*16..os*16+15 (which it wrote itself)
    f32x4 a2[4];
    #pragma unroll
    for (int js=0;js<4;js++) a2[js] = (f32x4){0.f,0.f,0.f,0.f};
    #pragma unroll
    for (int ks=0;ks<4;ks++){
      short8 av = *(const short8*)(ldt + (os*16 + lr)*136 + ks*32 + 8*q);
      #pragma unroll
      for (int js=0;js<4;js++){
        short8 bv = *(const short8*)(tf + ((size_t)(((blockIdx.x*4 + ks)*4 + js)*64 + lane))*8);
        a2[js] = __builtin_amdgcn_mfma_f32_16x16x32_bf16(av, bv, a2[js], 0,0,0);
      }
    }
    float* pp = xmp2 + ((size_t)blockIdx.x*64 + b)*4096;
    #pragma unroll
    for (int js=0;js<4;js++){
      #pragma unroll
      for (int r=0;r<4;r++)
        pp[(os*16 + 4*q + r)*64 + js*16 + lr] = a2[js][r];
    }
  } else {
    #pragma unroll
    for (int ls=0;ls<8;ls++){
      int l = l0 + ls*16 + lr;
      if (l < LL){
        #pragma unroll
        for (int r=0;r<4;r++){
          int o = os*16 + 4*q + r;
          dout[((size_t)(b*64 + o))*LL + l] = acc[ls][r] + bias[r];
        }
      }
    }
  }
}

extern "C" void kernel_launch(void* const* d_in, const int* in_sizes, int n_in,
                              void* d_out, int out_size, void* d_ws, size_t ws_size,
                              hipStream_t stream) {
  const float* x   = (const float*)d_in[0];
  const float* lw  = (const float*)d_in[1];
  const float* lb  = (const float*)d_in[2];
  const float* cw  = (const float*)d_in[3];
  const float* cb  = (const float*)d_in[4];
  const float* swr = (const float*)d_in[5];
  const float* swi = (const float*)d_in[6];

  char* ws = (char*)d_ws;
  size_t PL = (size_t)NB*BST;                 // 34,603,008 bytes per plane
  unsigned short* x0lc = (unsigned short*)(ws);
  unsigned short* x0t  = (unsigned short*)(ws + PL);       // lift->dft0; then partial buf A
  unsigned short* x1lc = (unsigned short*)(ws + 2*PL);
  unsigned short* x1t  = (unsigned short*)(ws + 3*PL);     // partial buf B
  unsigned short* tf   = (unsigned short*)(ws + 4*PL);
  unsigned short* tif  = (unsigned short*)(ws + 4*PL + 540672);
  unsigned short* wfch = (unsigned short*)(ws + 4*PL + 2*540672);
  unsigned short* wfcl = (unsigned short*)(ws + 4*PL + 2*540672 + 32768);
  unsigned short* wmh  = (unsigned short*)(ws + 4*PL + 2*540672 + 2*32768);
  unsigned short* wml  = (unsigned short*)(ws + 4*PL + 2*540672 + 2*32768 + 524288);
  float*          xm   = (float*)        (ws + 4*PL + 2*540672 + 2*32768 + 2*524288);

  float* pA = (float*)x0t;   // 33*262144 f32 = 34,603,008 B == plane size
  float* pB = (float*)x1t;

  k_tables<<<2176, 256,0,stream>>>(cw, tf, tif, wfch, wfcl);
  k_lift  <<<16896,256,0,stream>>>(x, lw, lb, x0lc, x0t);

  for (int k=0;k<NRL;k++){
    unsigned short* curlc = (k&1) ? x1lc : x0lc;
    unsigned short* nxtlc = (k&1) ? x0lc : x1lc;
    if (k == 0){
      float* xmp = (float*)x1lc;  // 12.6MB scratch, consumed before layer0 writes x1lc
      k_dft<<<dim3(DCH,NB),256,0,stream>>>(x0t, tf, xmp);
      k_red<<<512, 256,0,stream>>>(xmp, xm, DCH);
    } else {
      // partials written by previous k_layer: k=1 -> pA, k=2 -> pB, k=3 -> pA
      k_red<<<512, 256,0,stream>>>((k&1) ? pA : pB, xm, LCH);
    }
    k_mix<<<512, 256,0,stream>>>(xm, swr + (size_t)k*131072, swi + (size_t)k*131072, wmh, wml);
    // layer k (k<3) writes partials for layer k+1: k=0 -> pA, k=1 -> pB, k=2 -> pA
    float* pout = (k&1) ? pB : pA;
    k_layer<<<dim3(LCH,NB),256,0,stream>>>(curlc,
        wfch + (size_t)k*4096, wfcl + (size_t)k*4096, wmh, wml, tif, tf,
        cb + (size_t)k*64, nxtlc, pout, (float*)d_out, (k==NRL-1) ? 1 : 0);
  }
}